// Round 5
// baseline (309.117 us; speedup 1.0000x reference)
//
#include <hip/hip_runtime.h>

// proj_splat: project 48^3 voxel grid into 8 camera feature maps (64ch, 64x64),
// bilinear-sample, write (8, 64, 48^3) fp32.
//
// Strategy: per block = (1 camera, 2048-voxel tile). Stage each 16KB channel
// image in LDS (coalesced), gather bilinear taps from LDS (random access is
// cheap there), write float4 nontemporal stores. Projection computed once per
// voxel, amortized over 64 channels.

#define NR    8
#define FDIM  64
#define FH    64
#define FW    64
#define IMG   (FH * FW)            // 4096 floats = 16 KB
#define NVOX  48
#define NV    (NVOX * NVOX * NVOX) // 110592
#define CPP   2                    // channels per phase
#define NPH   (FDIM / CPP)         // 32 phases
#define TI    16
#define TJ    8
#define TK    16
#define THREADS 512

typedef float f32x4 __attribute__((ext_vector_type(4)));

__global__ __launch_bounds__(THREADS, 4) void proj_splat_kernel(
    const float* __restrict__ feats,   // [NR][FDIM][IMG]
    const float* __restrict__ Kcam,    // [2][4][3][4]
    const float* __restrict__ vmax,    // [2][3]
    const float* __restrict__ vmin,    // [2][3]
    float* __restrict__ out)           // [NR][FDIM][NV]
{
    __shared__ float lds[CPP][IMG + 4];   // +pad slot at [IMG] for clamped x-pair reads

    const int t = threadIdx.x;
    const int r = blockIdx.y;          // camera 0..7
    const int b = r >> 2;              // batch

    // tile decomposition: 3 x 6 x 3 tiles of (TI,TJ,TK)
    const int tile = blockIdx.x;       // 0..53
    const int ti = tile / 18;          // 0..2
    const int tj = (tile / 3) % 6;     // 0..5
    const int tk = tile % 3;           // 0..2

    // thread -> (i_loc 0..15, j_loc 0..7, k4 0..3); 4 consecutive k per thread
    const int i_loc = t >> 5;
    const int j_loc = (t >> 2) & 7;
    const int k4    = t & 3;

    const int vi  = ti * TI + i_loc;
    const int vj  = tj * TJ + j_loc;
    const int vk0 = tk * TK + k4 * 4;

    // ---- projection, once per voxel (4 voxels along k) ----
    const float inv = 1.0f / (float)(NVOX - 1);
    const float* vmn = vmin + b * 3;
    const float* vmx = vmax + b * 3;
    const float gx = vmn[0] + (vmx[0] - vmn[0]) * ((float)vi * inv);
    const float gy = vmn[1] + (vmx[1] - vmn[1]) * ((float)vj * inv);

    const float* K = Kcam + r * 12;
    // parts independent of z
    const float pxc = K[0] * gx + K[1] * gy + K[3];
    const float pyc = K[4] * gx + K[5] * gy + K[7];
    const float pzc = K[8] * gx + K[9] * gy + K[11];

    const float rsz = 0.25f;  // 64/256

    int   idxA[4], idxB[4];
    float wA0[4], wA1[4], wB0[4], wB1[4];
#pragma unroll
    for (int v = 0; v < 4; ++v) {
        const float gz = vmn[2] + (vmx[2] - vmn[2]) * ((float)(vk0 + v) * inv);
        const float px = pxc + K[2]  * gz;
        const float py = pyc + K[6]  * gz;
        const float pz = pzc + K[10] * gz;

        float imx = px / pz * rsz;
        float imy = py / pz * rsz;
        imx = fminf(fmaxf(imx, 0.0f), (float)(FW - 1));
        imy = fminf(fmaxf(imy, 0.0f), (float)(FH - 1));

        const float x0 = floorf(imx);
        const float x1 = fminf(x0 + 1.0f, (float)(FW - 1));
        const float y0 = floorf(imy);
        const float y1 = fminf(y0 + 1.0f, (float)(FH - 1));

        // wa=(x0,y0) wb=(x0,y1) wc=(x1,y0) wd=(x1,y1) — reference formulas, literally
        wA0[v] = (x1 - imx) * (y1 - imy);   // at idxA   = (y0,x0)
        wA1[v] = (imx - x0) * (y1 - imy);   // at idxA+1 = (y0,x0+1); 0 exactly when clamped
        wB0[v] = (x1 - imx) * (imy - y0);   // at idxB   = (y1,x0)
        wB1[v] = (imx - x0) * (imy - y0);   // at idxB+1

        const int ix0 = (int)x0;
        const int iy0 = (int)y0;
        const int iy1 = (int)y1;
        idxA[v] = iy0 * FW + ix0;
        idxB[v] = iy1 * FW + ix0;
    }

    // pad slots: read (idx+1)==IMG only when its weight is exactly 0; keep finite
    if (t == 0) { lds[0][IMG] = 0.0f; lds[1][IMG] = 0.0f; }

    const float* fbase = feats + (size_t)r * FDIM * IMG;
    float* obase = out + (size_t)r * FDIM * NV + ((vi * NVOX + vj) * NVOX + vk0);

    // ---- prologue: issue phase-0 staging loads (coalesced float4) ----
    f32x4 sreg[2][CPP];
#pragma unroll
    for (int ci = 0; ci < CPP; ++ci)
#pragma unroll
        for (int q = 0; q < 2; ++q)
            sreg[q][ci] = *reinterpret_cast<const f32x4*>(
                fbase + (size_t)ci * IMG + q * 2048 + t * 4);

    for (int p = 0; p < NPH; ++p) {
        // write staged regs -> LDS
#pragma unroll
        for (int ci = 0; ci < CPP; ++ci)
#pragma unroll
            for (int q = 0; q < 2; ++q)
                *reinterpret_cast<f32x4*>(&lds[ci][q * 2048 + t * 4]) = sreg[q][ci];
        __syncthreads();

        // issue next phase's loads early — they hide under this phase's compute
        if (p + 1 < NPH) {
#pragma unroll
            for (int ci = 0; ci < CPP; ++ci)
#pragma unroll
                for (int q = 0; q < 2; ++q)
                    sreg[q][ci] = *reinterpret_cast<const f32x4*>(
                        fbase + (size_t)((p + 1) * CPP + ci) * IMG + q * 2048 + t * 4);
        }

        // compute + store, 2 channels x 4 voxels
#pragma unroll
        for (int ci = 0; ci < CPP; ++ci) {
            const int c = p * CPP + ci;
            float acc[4];
#pragma unroll
            for (int v = 0; v < 4; ++v) {
                const float A0 = lds[ci][idxA[v]];
                const float A1 = lds[ci][idxA[v] + 1];
                const float B0 = lds[ci][idxB[v]];
                const float B1 = lds[ci][idxB[v] + 1];
                acc[v] = wA0[v] * A0 + wA1[v] * A1 + wB0[v] * B0 + wB1[v] * B1;
            }
            f32x4 o4 = { acc[0], acc[1], acc[2], acc[3] };
            __builtin_nontemporal_store(o4, reinterpret_cast<f32x4*>(obase + (size_t)c * NV));
        }
        __syncthreads();   // LDS reuse protection for next phase
    }
}

extern "C" void kernel_launch(void* const* d_in, const int* in_sizes, int n_in,
                              void* d_out, int out_size, void* d_ws, size_t ws_size,
                              hipStream_t stream) {
    const float* feats = (const float*)d_in[0];
    const float* Kcam  = (const float*)d_in[1];
    const float* vmax  = (const float*)d_in[2];
    const float* vmin  = (const float*)d_in[3];
    // d_in[4] = nvox (48), baked in as NVOX
    float* out = (float*)d_out;

    dim3 grid(54, NR);     // 54 tiles x 8 cameras = 432 blocks
    dim3 block(THREADS);
    proj_splat_kernel<<<grid, block, 0, stream>>>(feats, Kcam, vmax, vmin, out);
}

// Round 10
// 242.889 us; speedup vs baseline: 1.2727x; 1.2727x over previous
//
#include <hip/hip_runtime.h>

// proj_splat: project 48^3 voxel grid into 8 camera feature maps (64ch, 64x64),
// bilinear-sample, write (8, 64, 48^3) fp32.
//
// Structure: block = (camera, channel-pair, voxel-quarter). Stage the 2 channel
// images (32 KB) in LDS once, ONE barrier, then a free-running loop over this
// block's 27648 voxels: project (3 FMA/row via uniform constants), gather 4
// bilinear taps per channel from LDS (adjacent-pair reads -> ds_read2_b32),
// coalesced nontemporal scalar stores. 1024 blocks x 256 thr = 4 blocks/CU
// (LDS-limited), 16 waves/CU, no phase barriers.

#define NR    8
#define FDIM  64
#define FH    64
#define FW    64
#define IMG   (FH * FW)            // 4096 floats = 16 KB
#define NVOX  48
#define NV    (NVOX * NVOX * NVOX) // 110592
#define THREADS 256
#define QUARTERS 4
#define VPB   (NV / QUARTERS)      // 27648 voxels per block
#define ITERS (VPB / THREADS)      // 108

typedef float f32x4 __attribute__((ext_vector_type(4)));

__global__ __launch_bounds__(THREADS, 4) void proj_splat_kernel(
    const float* __restrict__ feats,   // [NR][FDIM][IMG]
    const float* __restrict__ Kcam,    // [2][4][3][4]
    const float* __restrict__ vmax,    // [2][3]
    const float* __restrict__ vmin,    // [2][3]
    float* __restrict__ out)           // [NR][FDIM][NV]
{
    // two channel images contiguous + 1 pad slot (reachable only as pixel
    // (63,63)+1 of channel 1; channel 0's overflow lands on ch1's pixel 0,
    // finite data, weight exactly 0)
    __shared__ float lds[2 * IMG + 1];

    const int t  = threadIdx.x;
    const int cp = blockIdx.x;         // channel pair 0..31
    const int qq = blockIdx.y;         // voxel quarter 0..3
    const int r  = blockIdx.z;         // camera 0..7
    const int b  = r >> 2;             // batch

    // ---- stage 2 channel images (contiguous 32 KB in global), coalesced ----
    const float* src = feats + ((size_t)r * FDIM + 2 * cp) * IMG;
#pragma unroll
    for (int q = 0; q < 8; ++q) {
        const int off = q * (THREADS * 4) + t * 4;
        *reinterpret_cast<f32x4*>(&lds[off]) =
            *reinterpret_cast<const f32x4*>(src + off);
    }
    if (t == 0) lds[2 * IMG] = 0.0f;   // pad for ch1 (63,63)+1; weight is 0
    __syncthreads();

    // ---- uniform per-block projection constants (live in SGPRs) ----
    // gx = vmn0 + ax*i etc; p = K @ [gx,gy,gz,1] collapsed to C + A*i + B*j + D*k
    const float inv = 1.0f / (float)(NVOX - 1);
    const float* vmn = vmin + b * 3;
    const float* vmx = vmax + b * 3;
    const float ax = (vmx[0] - vmn[0]) * inv;
    const float ay = (vmx[1] - vmn[1]) * inv;
    const float az = (vmx[2] - vmn[2]) * inv;
    const float* K = Kcam + r * 12;
    const float A0 = K[0] * ax, B0 = K[1] * ay, D0 = K[2]  * az;
    const float C0 = K[0] * vmn[0] + K[1] * vmn[1] + K[2]  * vmn[2] + K[3];
    const float A1 = K[4] * ax, B1 = K[5] * ay, D1 = K[6]  * az;
    const float C1 = K[4] * vmn[0] + K[5] * vmn[1] + K[6]  * vmn[2] + K[7];
    const float A2 = K[8] * ax, B2 = K[9] * ay, D2 = K[10] * az;
    const float C2 = K[8] * vmn[0] + K[9] * vmn[1] + K[10] * vmn[2] + K[11];

    float* o0 = out + ((size_t)r * FDIM + 2 * cp) * NV;
    float* o1 = o0 + NV;

    int n = qq * VPB + t;
    int i = n / (NVOX * NVOX);
    int j = (n / NVOX) % NVOX;
    int k = n % NVOX;

    for (int it = 0; it < ITERS; ++it) {
        const float fi = (float)i, fj = (float)j, fk = (float)k;
        const float px = C0 + A0 * fi + B0 * fj + D0 * fk;
        const float py = C1 + A1 * fi + B1 * fj + D1 * fk;
        const float pz = C2 + A2 * fi + B2 * fj + D2 * fk;

        const float rz = 0.25f / pz;       // rsz/z
        float imx = px * rz;
        float imy = py * rz;
        imx = fminf(fmaxf(imx, 0.0f), (float)(FW - 1));
        imy = fminf(fmaxf(imy, 0.0f), (float)(FH - 1));

        const float x0 = floorf(imx);
        const float x1 = fminf(x0 + 1.0f, (float)(FW - 1));
        const float y0 = floorf(imy);
        const float y1 = fminf(y0 + 1.0f, (float)(FH - 1));

        // reference weight formulas, literally (incl. the all-zero right-edge case)
        const float wa = (x1 - imx) * (y1 - imy);   // (y0,x0)
        const float wc = (imx - x0) * (y1 - imy);   // (y0,x0+1), 0 when clamped
        const float wb = (x1 - imx) * (imy - y0);   // (y1,x0)
        const float wd = (imx - x0) * (imy - y0);   // (y1,x0+1)

        const int ix0 = (int)x0;
        const int iy0 = (int)y0;
        const int iy1 = (int)y1;
        const int ia = iy0 * FW + ix0;
        const int ib = iy1 * FW + ix0;

        // channel 0: adjacent-pair LDS reads (ds_read2_b32)
        {
            const float a0 = lds[ia],       a1 = lds[ia + 1];
            const float b0 = lds[ib],       b1 = lds[ib + 1];
            const float res = wa * a0 + wc * a1 + wb * b0 + wd * b1;
            __builtin_nontemporal_store(res, o0 + n);
        }
        // channel 1
        {
            const float a0 = lds[IMG + ia], a1 = lds[IMG + ia + 1];
            const float b0 = lds[IMG + ib], b1 = lds[IMG + ib + 1];
            const float res = wa * a0 + wc * a1 + wb * b0 + wd * b1;
            __builtin_nontemporal_store(res, o1 + n);
        }

        // advance by THREADS=256 = 5*48 + 16 in (i,j,k)
        n += THREADS;
        k += 16;
        if (k >= NVOX) { k -= NVOX; j += 6; } else { j += 5; }
        if (j >= NVOX) { j -= NVOX; i += 1; }
    }
}

extern "C" void kernel_launch(void* const* d_in, const int* in_sizes, int n_in,
                              void* d_out, int out_size, void* d_ws, size_t ws_size,
                              hipStream_t stream) {
    const float* feats = (const float*)d_in[0];
    const float* Kcam  = (const float*)d_in[1];
    const float* vmax  = (const float*)d_in[2];
    const float* vmin  = (const float*)d_in[3];
    // d_in[4] = nvox (48), baked in as NVOX
    float* out = (float*)d_out;

    dim3 grid(FDIM / 2, QUARTERS, NR);   // 32 x 4 x 8 = 1024 blocks
    dim3 block(THREADS);
    proj_splat_kernel<<<grid, block, 0, stream>>>(feats, Kcam, vmax, vmin, out);
}